// Round 3
// baseline (440.295 us; speedup 1.0000x reference)
//
#include <hip/hip_runtime.h>
#include <math.h>

// Problem constants (match reference)
#define N_NEU   8192
#define IN_SZ   512
#define OUT_SZ  512
#define N4      (N_NEU / 4)          // 2048 float4 col-quads per row of W_in/synapses
#define OUT4    (OUT_SZ / 4)         // 128 quads per W_out row
#define KPB     64                   // synapse k-rows per K1 block
#define WPB     4                    // W_in k-rows per K1 block (512 / 128 tiles)
#define SYN_TILES (N_NEU / KPB)      // 128 -> grid (8,128) = 1024 blocks = 4/CU
#define K2_KPB  16                   // k-rows per K2 out-gemv tile
#define OTILES  (N_NEU / K2_KPB)     // 512 -> 2 blocks/CU
constexpr float TAU_INV = 0.1f;
constexpr float G_GAIN  = 1.5f;

// ---------------------------------------------------------------------------
// K0: zero out[0:8704]. out[512:8704] is K1's atomic accumulator (drive sums),
//     out[0:512] is K2's atomic accumulator (final output). 34*256 = 8704.
// ---------------------------------------------------------------------------
__global__ __launch_bounds__(256)
void zero_kernel(float* __restrict__ out) {
    out[blockIdx.x * 256 + threadIdx.x] = 0.0f;
}

// ---------------------------------------------------------------------------
// K1: split-K GEMV, no workspace. Block (bx, by) owns col-stripe bx (1024 cols)
//     and k-rows: 64 synapse rows [by*64, ...) PLUS 4 W_in rows [by*4, ...).
//     KPB=64 -> 1024 blocks = 4 blocks/CU = 4 waves/SIMD for latency hiding
//     (vs 2 at KPB=128). acc -> atomicAdd into out[512 + col].
//     1024*1024 = 1.05M fp32 atomics onto a 32 KB L2-resident region.
// grid = (8, 128), block = 256
// ---------------------------------------------------------------------------
__global__ __launch_bounds__(256)
void accum_kernel(const float* __restrict__ pot,
                  const float* __restrict__ inputs,
                  const float* __restrict__ synapses,
                  const float* __restrict__ W_in,
                  float* __restrict__ out) {
    __shared__ float xs[KPB + WPB];
    const int bx = blockIdx.x, by = blockIdx.y;
    const int tid = threadIdx.x;
    const int k0 = by * KPB;       // synapse row base
    const int w0 = by * WPB;       // W_in row base
    if (tid < KPB)                xs[tid] = G_GAIN * tanhf(pot[k0 + tid]);
    else if (tid < KPB + WPB)     xs[tid] = inputs[w0 + (tid - KPB)];
    __syncthreads();

    const int col4 = bx * 256 + tid;
    const float4* Sp = (const float4*)synapses + (size_t)k0 * N4 + col4;
    const float4* Wp = (const float4*)W_in     + (size_t)w0 * N4 + col4;

    float4 acc = make_float4(0.f, 0.f, 0.f, 0.f);
#pragma unroll 8
    for (int i = 0; i < KPB; ++i) {
        float  s = xs[i];
        float4 m = Sp[(size_t)i * N4];
        acc.x = fmaf(s, m.x, acc.x);
        acc.y = fmaf(s, m.y, acc.y);
        acc.z = fmaf(s, m.z, acc.z);
        acc.w = fmaf(s, m.w, acc.w);
    }
#pragma unroll
    for (int i = 0; i < WPB; ++i) {
        float  s = xs[KPB + i];
        float4 m = Wp[(size_t)i * N4];
        acc.x = fmaf(s, m.x, acc.x);
        acc.y = fmaf(s, m.y, acc.y);
        acc.z = fmaf(s, m.z, acc.z);
        acc.w = fmaf(s, m.w, acc.w);
    }
    float* op = out + OUT_SZ + (size_t)col4 * 4;
    atomicAdd(op + 0, acc.x);
    atomicAdd(op + 1, acc.y);
    atomicAdd(op + 2, acc.z);
    atomicAdd(op + 3, acc.w);
}

// ---------------------------------------------------------------------------
// K2: 512 blocks, 16 rows each (2 blocks/CU). Read accumulated drive
//     s = out[512+j] (single load), pot_new in-place (exclusive rows),
//     gen = tanh(pot_new), 16-row W_out gemv slice, atomics into out[0:512].
// block = 128 (t indexes the 128 float4 output columns)
// ---------------------------------------------------------------------------
__global__ __launch_bounds__(128)
void finish_kernel(const float* __restrict__ pot,
                   const float* __restrict__ W_out,
                   float* __restrict__ out) {
    __shared__ float xs[K2_KPB];
    const int b = blockIdx.x;
    const int t = threadIdx.x;
    const int k0 = b * K2_KPB;

    if (t < K2_KPB) {
        float s  = out[OUT_SZ + k0 + t];      // accumulated G*(r@syn) + drive
        float p  = pot[k0 + t];
        float pn = p + (s - p) * TAU_INV;
        out[OUT_SZ + k0 + t] = pn;            // pot_new (exclusive rows)
        xs[t] = tanhf(pn);
    }
    __syncthreads();

    const float4* Wp = (const float4*)W_out + (size_t)k0 * OUT4 + t;
    float4 acc = make_float4(0.f, 0.f, 0.f, 0.f);
#pragma unroll
    for (int i = 0; i < K2_KPB; ++i) {
        float  sx = xs[i];
        float4 m  = Wp[(size_t)i * OUT4];
        acc.x = fmaf(sx, m.x, acc.x);
        acc.y = fmaf(sx, m.y, acc.y);
        acc.z = fmaf(sx, m.z, acc.z);
        acc.w = fmaf(sx, m.w, acc.w);
    }
    float* op = out + (size_t)t * 4;
    atomicAdd(op + 0, acc.x);
    atomicAdd(op + 1, acc.y);
    atomicAdd(op + 2, acc.z);
    atomicAdd(op + 3, acc.w);
}

// ---------------------------------------------------------------------------
extern "C" void kernel_launch(void* const* d_in, const int* in_sizes, int n_in,
                              void* d_out, int out_size, void* d_ws, size_t ws_size,
                              hipStream_t stream) {
    const float* inputs   = (const float*)d_in[0];   // [512]
    const float* pot      = (const float*)d_in[1];   // [8192]
    const float* W_in     = (const float*)d_in[2];   // [512, 8192]
    const float* synapses = (const float*)d_in[3];   // [8192, 8192]
    const float* W_out    = (const float*)d_in[4];   // [8192, 512]

    float* out = (float*)d_out;          // [0:512] output, [512:8704] pot_new
    (void)d_ws; (void)ws_size;           // workspace intentionally UNUSED

    // K0: zero both atomic accumulators (8704 floats)
    zero_kernel<<<dim3((OUT_SZ + N_NEU) / 256), dim3(256), 0, stream>>>(out);

    // K1: 8 col-stripes x 128 k-tiles (64 synapse + 4 W_in rows each)
    accum_kernel<<<dim3(8, SYN_TILES), dim3(256), 0, stream>>>(
        pot, inputs, synapses, W_in, out);

    // K2: 512 tiles of 16 rows: pot_new + out-gemv with atomics into out[0:512]
    finish_kernel<<<dim3(OTILES), dim3(128), 0, stream>>>(pot, W_out, out);
}

// Round 4
// 392.017 us; speedup vs baseline: 1.1232x; 1.1232x over previous
//
#include <hip/hip_runtime.h>
#include <math.h>

// Problem constants (match reference)
#define N_NEU   8192
#define IN_SZ   512
#define OUT_SZ  512
#define N4      (N_NEU / 4)          // 2048 float4 col-quads per row of W_in/synapses
#define OUT4    (OUT_SZ / 4)         // 128 quads per W_out row
#define KPB     128                  // synapse k-rows per K1 block
#define WPB     8                    // W_in k-rows per K1 block
#define SYN_TILES (N_NEU / KPB)      // 64 -> grid (8,64) = 512 blocks = 2/CU
#define K2_ROWS 64                   // rows per K2 block
#define K2_BLKS (N_NEU / K2_ROWS)    // 128
constexpr float TAU_INV = 0.1f;
constexpr float G_GAIN  = 1.5f;

// ---------------------------------------------------------------------------
// K1: split-K GEMV. Block (bx,by) owns col-stripe bx (1024 cols) and k-rows
//     {128 synapse rows by*128.., 8 W_in rows by*8..}. Partial sums stored
//     NON-ATOMICALLY as coalesced float4 into P4[by][col4] (2 MB workspace,
//     L2/LLC-resident). No zero kernel needed: block (0,0) zeroes out[0:512]
//     for K2's atomics (K1->K2 kernel boundary orders it).
//     Atomic count in K1: ZERO (round 3 showed ~50 ns marginal cost/atomic).
// grid = (8, 64), block = 256
// ---------------------------------------------------------------------------
__global__ __launch_bounds__(256)
void accum_kernel(const float* __restrict__ pot,
                  const float* __restrict__ inputs,
                  const float* __restrict__ synapses,
                  const float* __restrict__ W_in,
                  float4* __restrict__ P4,      // [64][2048] float4
                  float* __restrict__ out) {
    __shared__ float xs[KPB + WPB];
    const int bx = blockIdx.x, by = blockIdx.y;
    const int tid = threadIdx.x;
    const int k0 = by * KPB;       // synapse row base
    const int w0 = by * WPB;       // W_in row base
    if (tid < KPB)                xs[tid] = G_GAIN * tanhf(pot[k0 + tid]);
    else if (tid < KPB + WPB)     xs[tid] = inputs[w0 + (tid - KPB)];
    if (bx == 0 && by == 0 && tid < 128)
        ((float4*)out)[tid] = make_float4(0.f, 0.f, 0.f, 0.f);
    __syncthreads();

    const int col4 = bx * 256 + tid;
    const float4* Sp = (const float4*)synapses + (size_t)k0 * N4 + col4;
    const float4* Wp = (const float4*)W_in     + (size_t)w0 * N4 + col4;

    float4 acc = make_float4(0.f, 0.f, 0.f, 0.f);
#pragma unroll 8
    for (int i = 0; i < KPB; ++i) {
        float  s = xs[i];
        float4 m = Sp[(size_t)i * N4];
        acc.x = fmaf(s, m.x, acc.x);
        acc.y = fmaf(s, m.y, acc.y);
        acc.z = fmaf(s, m.z, acc.z);
        acc.w = fmaf(s, m.w, acc.w);
    }
#pragma unroll
    for (int i = 0; i < WPB; ++i) {
        float  s = xs[KPB + i];
        float4 m = Wp[(size_t)i * N4];
        acc.x = fmaf(s, m.x, acc.x);
        acc.y = fmaf(s, m.y, acc.y);
        acc.z = fmaf(s, m.z, acc.z);
        acc.w = fmaf(s, m.w, acc.w);
    }
    P4[(size_t)by * N4 + col4] = acc;          // coalesced private store
}

// ---------------------------------------------------------------------------
// K2: 128 blocks x 256 thr, 64 rows each.
//     Phase A: reduce the 64 k-tile partials per row. Wave q (t>>6) sums 16
//       tiles with coalesced 256B reads P[(q*16+p)*8192 + k0 + lane]; LDS
//       combine -> drive; pot_new in out[512+], xs = tanh(pot_new).
//     Phase B: 64-row W_out gemv with rows SPLIT across thread halves
//       (h = t>>7 handles rows h*32..+32) -> all 4 waves busy, serial chain
//       halved; LDS-combine halves; 128 threads atomicAdd out[0:512]
//       (65K atomics total, round-1-proven level).
// grid = 128, block = 256
// ---------------------------------------------------------------------------
__global__ __launch_bounds__(256)
void finish_kernel(const float* __restrict__ pot,
                   const float* __restrict__ P,     // [64][8192] floats
                   const float* __restrict__ W_out,
                   float* __restrict__ out) {
    __shared__ float  red[256];
    __shared__ float  xs[K2_ROWS];
    __shared__ float4 hi[128];
    const int b = blockIdx.x;
    const int t = threadIdx.x;
    const int k0 = b * K2_ROWS;
    const int r = t & 63;           // row within tile (= lane)
    const int q = t >> 6;           // wave id: which 16 partial-tiles

    float s = 0.f;
#pragma unroll
    for (int p = 0; p < 16; ++p)
        s += P[(size_t)(q * 16 + p) * N_NEU + k0 + r];
    red[t] = s;
    __syncthreads();

    if (t < K2_ROWS) {
        float drive = red[t] + red[64 + t] + red[128 + t] + red[192 + t];
        float pv = pot[k0 + t];
        float pn = pv + (drive - pv) * TAU_INV;
        out[OUT_SZ + k0 + t] = pn;             // pot_new (exclusive rows)
        xs[t] = tanhf(pn);
    }
    __syncthreads();

    const int c4 = t & 127;         // output col4
    const int h  = t >> 7;          // row-half: 0 -> rows 0..31, 1 -> 32..63
    const float4* Wp = (const float4*)W_out + (size_t)(k0 + h * 32) * OUT4 + c4;
    float4 acc = make_float4(0.f, 0.f, 0.f, 0.f);
#pragma unroll 8
    for (int i = 0; i < 32; ++i) {
        float  sx = xs[h * 32 + i];
        float4 m  = Wp[(size_t)i * OUT4];
        acc.x = fmaf(sx, m.x, acc.x);
        acc.y = fmaf(sx, m.y, acc.y);
        acc.z = fmaf(sx, m.z, acc.z);
        acc.w = fmaf(sx, m.w, acc.w);
    }
    if (h == 1) hi[c4] = acc;
    __syncthreads();
    if (h == 0) {
        float4 o = hi[c4];
        acc.x += o.x; acc.y += o.y; acc.z += o.z; acc.w += o.w;
        float* op = out + (size_t)c4 * 4;
        atomicAdd(op + 0, acc.x);
        atomicAdd(op + 1, acc.y);
        atomicAdd(op + 2, acc.z);
        atomicAdd(op + 3, acc.w);
    }
}

// ---------------------------------------------------------------------------
extern "C" void kernel_launch(void* const* d_in, const int* in_sizes, int n_in,
                              void* d_out, int out_size, void* d_ws, size_t ws_size,
                              hipStream_t stream) {
    const float* inputs   = (const float*)d_in[0];   // [512]
    const float* pot      = (const float*)d_in[1];   // [8192]
    const float* W_in     = (const float*)d_in[2];   // [512, 8192]
    const float* synapses = (const float*)d_in[3];   // [8192, 8192]
    const float* W_out    = (const float*)d_in[4];   // [8192, 512]

    float* out = (float*)d_out;          // [0:512] output, [512:8704] pot_new
    float* P   = (float*)d_ws;           // [64][8192] partials = 2 MB

    // K1: 8 col-stripes x 64 k-tiles, non-atomic partials; zeroes out[0:512]
    accum_kernel<<<dim3(8, SYN_TILES), dim3(256), 0, stream>>>(
        pot, inputs, synapses, W_in, (float4*)P, out);

    // K2: 128 tiles of 64 rows: coalesced reduce + pot_new + split-row gemv
    finish_kernel<<<dim3(K2_BLKS), dim3(256), 0, stream>>>(
        pot, P, W_out, out);
}